// Round 1
// baseline (380.423 us; speedup 1.0000x reference)
//
#include <hip/hip_runtime.h>

#define TSEQ 512
#define CDIM 512
#define NH 8
#define HS 64
#define BBATCH 32
#define MROWS (BBATCH * TSEQ)   // 16384

typedef unsigned short u16;
typedef __bf16 bf16x8 __attribute__((ext_vector_type(8)));
typedef float f32x4 __attribute__((ext_vector_type(4)));

// round-to-nearest-even fp32 -> bf16 bits
__device__ __forceinline__ u16 f2b(float f) {
  union { float f; unsigned u; } v; v.f = f;
  unsigned r = (v.u + 0x7fffu + ((v.u >> 16) & 1u)) >> 16;
  return (u16)r;
}

// ---------------- prep kernels ----------------

__global__ __launch_bounds__(256) void conv_x(const float* __restrict__ x,
                                              u16* __restrict__ xb) {
  int i = blockIdx.x * 256 + threadIdx.x;       // MROWS*CDIM/4 elements
  float4 v = reinterpret_cast<const float4*>(x)[i];
  ushort4 o;
  o.x = f2b(v.x); o.y = f2b(v.y); o.z = f2b(v.z); o.w = f2b(v.w);
  reinterpret_cast<ushort4*>(xb)[i] = o;
}

// transpose Wq,Wk,Wv -> wtA[1536][512] bf16 ; Wo -> woT[512][512] bf16
__global__ __launch_bounds__(256) void transpose_w(const float* __restrict__ wq,
                                                   const float* __restrict__ wk,
                                                   const float* __restrict__ wv,
                                                   const float* __restrict__ wo,
                                                   u16* __restrict__ wtA,
                                                   u16* __restrict__ woT) {
  __shared__ float tile[32][33];
  int mat = blockIdx.z;
  const float* src = (mat == 0) ? wq : (mat == 1) ? wk : (mat == 2) ? wv : wo;
  u16* dst = (mat < 3) ? (wtA + (size_t)mat * CDIM * CDIM) : woT;
  int kb = blockIdx.x * 32, nb = blockIdx.y * 32;
  int tx = threadIdx.x, ty = threadIdx.y;
#pragma unroll
  for (int rr = 0; rr < 32; rr += 8)
    tile[ty + rr][tx] = src[(size_t)(kb + ty + rr) * CDIM + nb + tx];
  __syncthreads();
#pragma unroll
  for (int rr = 0; rr < 32; rr += 8)
    dst[(size_t)(nb + ty + rr) * CDIM + kb + tx] = f2b(tile[tx][ty + rr]);
}

__global__ __launch_bounds__(256) void rope_tab(float* __restrict__ cosT,
                                                float* __restrict__ sinT) {
  int i = blockIdx.x * 256 + threadIdx.x;       // 512*32
  int t = i >> 5, f = i & 31;
  float inv = __powf(10000.0f, -(float)f / 32.0f);
  float ang = (float)t * inv;
  cosT[i] = cosf(ang);
  sinT[i] = sinf(ang);
}

// ---------------- fused QKV GEMM + RoPE ----------------
// grid (MROWS/64, 1536/64), block 256. Wave w computes rows m0+w*16..+15, cols n0..n0+63.
__global__ __launch_bounds__(256) void qkv_gemm(const u16* __restrict__ xb,
                                                const u16* __restrict__ wtA,
                                                const float* __restrict__ cosT,
                                                const float* __restrict__ sinT,
                                                u16* __restrict__ Qb,
                                                u16* __restrict__ Kb,
                                                u16* __restrict__ VT) {
  const int lane = threadIdx.x & 63, wid = threadIdx.x >> 6;
  const int l16 = lane & 15, lg = lane >> 4;
  const int m0 = blockIdx.x * 64 + wid * 16;
  const int n0 = blockIdx.y * 64;

  f32x4 acc[4] = {};
  const u16* arow = xb + (size_t)(m0 + l16) * CDIM + lg * 8;
  for (int k = 0; k < CDIM; k += 32) {
    bf16x8 af = *reinterpret_cast<const bf16x8*>(arow + k);
#pragma unroll
    for (int nf = 0; nf < 4; ++nf) {
      bf16x8 bfv = *reinterpret_cast<const bf16x8*>(
          wtA + (size_t)(n0 + nf * 16 + l16) * CDIM + k + lg * 8);
      acc[nf] = __builtin_amdgcn_mfma_f32_16x16x32_bf16(af, bfv, acc[nf], 0, 0, 0);
    }
  }

  const int mat = n0 >> 9;        // 0:Q 1:K 2:V
  const int nc = n0 & 511;
  if (mat < 2) {
    u16* dst = (mat == 0) ? Qb : Kb;
#pragma unroll
    for (int nf = 0; nf < 4; ++nf) {
      int col = nc + nf * 16 + l16;
      int dd = col & 63;
      int fi = dd >> 1;
#pragma unroll
      for (int r = 0; r < 4; ++r) {
        int row = m0 + lg * 4 + r;
        int t = row & (TSEQ - 1);
        float v = acc[nf][r];
        float o = __shfl_xor(v, 1);          // RoPE partner column
        float c = cosT[t * 32 + fi];
        float sn = sinT[t * 32 + fi];
        float res = (dd & 1) ? (v * c + o * sn) : (v * c - o * sn);
        dst[(size_t)row * CDIM + col] = f2b(res);
      }
    }
  } else {
    // V: store transposed as VT[(b*8+h)*64+d][t]
#pragma unroll
    for (int nf = 0; nf < 4; ++nf) {
      int col = nc + nf * 16 + l16;
      int hh = col >> 6, dd = col & 63;
      int bidx = m0 >> 9;
      int tb = (m0 & (TSEQ - 1)) + lg * 4;
      ushort4 pk;
      pk.x = f2b(acc[nf][0]); pk.y = f2b(acc[nf][1]);
      pk.z = f2b(acc[nf][2]); pk.w = f2b(acc[nf][3]);
      *reinterpret_cast<ushort4*>(
          VT + (size_t)((bidx * NH + hh) * HS + dd) * TSEQ + tb) = pk;
    }
  }
}

// ---------------- flash attention ----------------
// grid (B*H, TSEQ/64), block 256. Each wave owns 16 q-rows.
__global__ __launch_bounds__(256) void attn_kern(const u16* __restrict__ Qb,
                                                 const u16* __restrict__ Kb,
                                                 const u16* __restrict__ VT,
                                                 u16* __restrict__ att) {
  __shared__ __align__(16) u16 plds[4][16][32];
  const int lane = threadIdx.x & 63, wid = threadIdx.x >> 6;
  const int l16 = lane & 15, lg = lane >> 4;
  const int bh = blockIdx.x, b = bh >> 3, h = bh & 7;
  const int q0 = blockIdx.y * 64 + wid * 16;

  bf16x8 qf[2];
#pragma unroll
  for (int dc = 0; dc < 2; ++dc)
    qf[dc] = *reinterpret_cast<const bf16x8*>(
        Qb + (size_t)(b * TSEQ + q0 + l16) * CDIM + h * HS + dc * 32 + lg * 8);

  float m_r[4], l_r[4];
  f32x4 of[4] = {};
#pragma unroll
  for (int r = 0; r < 4; ++r) { m_r[r] = -1e30f; l_r[r] = 0.0f; }

  const int nkt = (q0 + 16 + 31) >> 5;
  for (int kt = 0; kt < nkt; ++kt) {
    f32x4 s[2] = {};
#pragma unroll
    for (int dc = 0; dc < 2; ++dc) {
      bf16x8 kf0 = *reinterpret_cast<const bf16x8*>(
          Kb + (size_t)(b * TSEQ + kt * 32 + l16) * CDIM + h * HS + dc * 32 + lg * 8);
      bf16x8 kf1 = *reinterpret_cast<const bf16x8*>(
          Kb + (size_t)(b * TSEQ + kt * 32 + 16 + l16) * CDIM + h * HS + dc * 32 + lg * 8);
      s[0] = __builtin_amdgcn_mfma_f32_16x16x32_bf16(qf[dc], kf0, s[0], 0, 0, 0);
      s[1] = __builtin_amdgcn_mfma_f32_16x16x32_bf16(qf[dc], kf1, s[1], 0, 0, 0);
    }
    float pm[4];
#pragma unroll
    for (int r = 0; r < 4; ++r) {
      int qg = q0 + lg * 4 + r;
      float v0 = s[0][r] * 0.125f;
      float v1 = s[1][r] * 0.125f;
      if (kt * 32 + l16 > qg) v0 = -1e30f;
      if (kt * 32 + 16 + l16 > qg) v1 = -1e30f;
      s[0][r] = v0; s[1][r] = v1;
      pm[r] = fmaxf(v0, v1);
    }
#pragma unroll
    for (int off = 1; off < 16; off <<= 1)
#pragma unroll
      for (int r = 0; r < 4; ++r) pm[r] = fmaxf(pm[r], __shfl_xor(pm[r], off));
#pragma unroll
    for (int r = 0; r < 4; ++r) {
      float mn = fmaxf(m_r[r], pm[r]);
      float alpha = __expf(m_r[r] - mn);
      m_r[r] = mn;
      float p0 = __expf(s[0][r] - mn);
      float p1 = __expf(s[1][r] - mn);
      s[0][r] = p0; s[1][r] = p1;
      float ts = p0 + p1;
#pragma unroll
      for (int off = 1; off < 16; off <<= 1) ts += __shfl_xor(ts, off);
      l_r[r] = l_r[r] * alpha + ts;
#pragma unroll
      for (int d = 0; d < 4; ++d) of[d][r] *= alpha;
    }
    // P (C-layout) -> LDS -> A-layout fragment
#pragma unroll
    for (int r = 0; r < 4; ++r) {
      plds[wid][lg * 4 + r][l16]      = f2b(s[0][r]);
      plds[wid][lg * 4 + r][16 + l16] = f2b(s[1][r]);
    }
    bf16x8 pf = *reinterpret_cast<const bf16x8*>(&plds[wid][l16][lg * 8]);
#pragma unroll
    for (int d = 0; d < 4; ++d) {
      bf16x8 vf = *reinterpret_cast<const bf16x8*>(
          VT + (size_t)(bh * HS + d * 16 + l16) * TSEQ + kt * 32 + lg * 8);
      of[d] = __builtin_amdgcn_mfma_f32_16x16x32_bf16(pf, vf, of[d], 0, 0, 0);
    }
  }
#pragma unroll
  for (int d = 0; d < 4; ++d)
#pragma unroll
    for (int r = 0; r < 4; ++r) {
      float v = of[d][r] / l_r[r];
      att[(size_t)(b * TSEQ + q0 + lg * 4 + r) * CDIM + h * HS + d * 16 + l16] = f2b(v);
    }
}

// ---------------- output projection ----------------
__global__ __launch_bounds__(256) void out_gemm(const u16* __restrict__ A,
                                                const u16* __restrict__ WT,
                                                const float* __restrict__ bias,
                                                float* __restrict__ out) {
  const int lane = threadIdx.x & 63, wid = threadIdx.x >> 6;
  const int l16 = lane & 15, lg = lane >> 4;
  const int m0 = blockIdx.x * 64 + wid * 16;
  const int n0 = blockIdx.y * 64;
  f32x4 acc[4] = {};
  const u16* arow = A + (size_t)(m0 + l16) * CDIM + lg * 8;
  for (int k = 0; k < CDIM; k += 32) {
    bf16x8 af = *reinterpret_cast<const bf16x8*>(arow + k);
#pragma unroll
    for (int nf = 0; nf < 4; ++nf) {
      bf16x8 bfv = *reinterpret_cast<const bf16x8*>(
          WT + (size_t)(n0 + nf * 16 + l16) * CDIM + k + lg * 8);
      acc[nf] = __builtin_amdgcn_mfma_f32_16x16x32_bf16(af, bfv, acc[nf], 0, 0, 0);
    }
  }
#pragma unroll
  for (int nf = 0; nf < 4; ++nf) {
    int col = n0 + nf * 16 + l16;
    float bv = bias[col];
#pragma unroll
    for (int r = 0; r < 4; ++r) {
      int row = m0 + lg * 4 + r;
      out[(size_t)row * CDIM + col] = acc[nf][r] + bv;
    }
  }
}

// ---------------- launcher ----------------
extern "C" void kernel_launch(void* const* d_in, const int* in_sizes, int n_in,
                              void* d_out, int out_size, void* d_ws, size_t ws_size,
                              hipStream_t stream) {
  const float* x  = (const float*)d_in[0];
  const float* Wq = (const float*)d_in[1];
  const float* Wk = (const float*)d_in[2];
  const float* Wv = (const float*)d_in[3];
  const float* Wo = (const float*)d_in[4];
  const float* bo = (const float*)d_in[5];
  float* out = (float*)d_out;

  char* p = (char*)d_ws;
  const size_t big = (size_t)MROWS * CDIM * 2;     // 16.78 MB per bf16 activation
  u16* xb   = (u16*)p;  p += big;
  u16* wtA  = (u16*)p;  p += (size_t)3 * CDIM * CDIM * 2;
  u16* woT  = (u16*)p;  p += (size_t)CDIM * CDIM * 2;
  float* cosT = (float*)p; p += (size_t)TSEQ * 32 * 4;
  float* sinT = (float*)p; p += (size_t)TSEQ * 32 * 4;
  u16* Qb   = (u16*)p;  p += big;
  u16* Kb   = (u16*)p;  p += big;
  u16* VT   = (u16*)p;  p += big;
  u16* att  = (u16*)p;  p += big;

  hipLaunchKernelGGL(conv_x, dim3(MROWS * CDIM / 4 / 256), dim3(256), 0, stream, x, xb);
  hipLaunchKernelGGL(transpose_w, dim3(16, 16, 4), dim3(32, 8), 0, stream,
                     Wq, Wk, Wv, Wo, wtA, woT);
  hipLaunchKernelGGL(rope_tab, dim3(TSEQ * 32 / 256), dim3(256), 0, stream, cosT, sinT);
  hipLaunchKernelGGL(qkv_gemm, dim3(MROWS / 64, 1536 / 64), dim3(256), 0, stream,
                     xb, wtA, cosT, sinT, Qb, Kb, VT);
  hipLaunchKernelGGL(attn_kern, dim3(BBATCH * NH, TSEQ / 64), dim3(256), 0, stream,
                     Qb, Kb, VT, att);
  hipLaunchKernelGGL(out_gemm, dim3(MROWS / 64, CDIM / 64), dim3(256), 0, stream,
                     att, woT, bo, out);
}

// Round 2
// 156.183 us; speedup vs baseline: 2.4357x; 2.4357x over previous
//
#include <hip/hip_runtime.h>

#define TSEQ 512
#define CDIM 512
#define NH 8
#define HS 64
#define BBATCH 32
#define MROWS (BBATCH * TSEQ)   // 16384

#define BM 128
#define BN 128
#define BK 32

typedef unsigned short u16;
typedef __bf16 bf16x8 __attribute__((ext_vector_type(8)));
typedef float f32x4 __attribute__((ext_vector_type(4)));

// round-to-nearest-even fp32 -> bf16 bits
__device__ __forceinline__ u16 f2b(float f) {
  union { float f; unsigned u; } v; v.f = f;
  unsigned r = (v.u + 0x7fffu + ((v.u >> 16) & 1u)) >> 16;
  return (u16)r;
}

__device__ __forceinline__ void gload_lds16(const u16* g, u16* l) {
  __builtin_amdgcn_global_load_lds(
      (const __attribute__((address_space(1))) void*)g,
      (__attribute__((address_space(3))) void*)l, 16, 0, 0);
}

// ---------------- prep kernels ----------------

__global__ __launch_bounds__(256) void conv_x(const float* __restrict__ x,
                                              u16* __restrict__ xb) {
  int i = blockIdx.x * 256 + threadIdx.x;       // MROWS*CDIM/4 elements
  float4 v = reinterpret_cast<const float4*>(x)[i];
  ushort4 o;
  o.x = f2b(v.x); o.y = f2b(v.y); o.z = f2b(v.z); o.w = f2b(v.w);
  reinterpret_cast<ushort4*>(xb)[i] = o;
}

// transpose Wq,Wk,Wv -> wtA[1536][512] bf16 ; Wo -> woT[512][512] bf16
__global__ __launch_bounds__(256) void transpose_w(const float* __restrict__ wq,
                                                   const float* __restrict__ wk,
                                                   const float* __restrict__ wv,
                                                   const float* __restrict__ wo,
                                                   u16* __restrict__ wtA,
                                                   u16* __restrict__ woT) {
  __shared__ float tile[32][33];
  int mat = blockIdx.z;
  const float* src = (mat == 0) ? wq : (mat == 1) ? wk : (mat == 2) ? wv : wo;
  u16* dst = (mat < 3) ? (wtA + (size_t)mat * CDIM * CDIM) : woT;
  int kb = blockIdx.x * 32, nb = blockIdx.y * 32;
  int tx = threadIdx.x, ty = threadIdx.y;
#pragma unroll
  for (int rr = 0; rr < 32; rr += 8)
    tile[ty + rr][tx] = src[(size_t)(kb + ty + rr) * CDIM + nb + tx];
  __syncthreads();
#pragma unroll
  for (int rr = 0; rr < 32; rr += 8)
    dst[(size_t)(nb + ty + rr) * CDIM + kb + tx] = f2b(tile[tx][ty + rr]);
}

__global__ __launch_bounds__(256) void rope_tab(float* __restrict__ cosT,
                                                float* __restrict__ sinT) {
  int i = blockIdx.x * 256 + threadIdx.x;       // 512*32
  int t = i >> 5, f = i & 31;
  float inv = __powf(10000.0f, -(float)f / 32.0f);
  float ang = (float)t * inv;
  cosT[i] = cosf(ang);
  sinT[i] = sinf(ang);
}

// ---------------- fused QKV GEMM + RoPE (m97 structure) ----------------
// grid (MROWS/BM, 1536/BN), block 256 (4 waves, each 64x64 of the 128x128 tile)
__global__ __launch_bounds__(256) void qkv_gemm(const u16* __restrict__ xb,
                                                const u16* __restrict__ wtA,
                                                const float* __restrict__ cosT,
                                                const float* __restrict__ sinT,
                                                u16* __restrict__ Qb,
                                                u16* __restrict__ Kb,
                                                u16* __restrict__ VT) {
  __shared__ __align__(16) u16 lsA[BM * BK];   // 8 KB
  __shared__ __align__(16) u16 lsB[BN * BK];   // 8 KB
  const int tid = threadIdx.x;
  const int lane = tid & 63;
  const int l16 = lane & 15, lg = lane >> 4;
  const int wid = tid >> 6;
  const int wr = wid >> 1, wc = wid & 1;
  const int m0 = blockIdx.x * BM;
  const int n0 = blockIdx.y * BN;

  const u16* gA = xb + (size_t)m0 * CDIM;
  const u16* gB = wtA + (size_t)n0 * CDIM;

  f32x4 acc[4][4] = {};

  for (int kt = 0; kt < CDIM; kt += BK) {
#pragma unroll
    for (int c = 0; c < 2; ++c) {
      int flat = c * 2048 + tid * 8;           // element index in 128x32 tile
      int row = flat >> 5, col = flat & 31;
      gload_lds16(gA + (size_t)row * CDIM + kt + col, lsA + flat);
      gload_lds16(gB + (size_t)row * CDIM + kt + col, lsB + flat);
    }
    __syncthreads();
    bf16x8 af[4], bfr[4];
#pragma unroll
    for (int m = 0; m < 4; ++m)
      af[m] = *reinterpret_cast<const bf16x8*>(lsA + (wr * 64 + m * 16 + l16) * BK + lg * 8);
#pragma unroll
    for (int n = 0; n < 4; ++n)
      bfr[n] = *reinterpret_cast<const bf16x8*>(lsB + (wc * 64 + n * 16 + l16) * BK + lg * 8);
#pragma unroll
    for (int m = 0; m < 4; ++m)
#pragma unroll
      for (int n = 0; n < 4; ++n)
        acc[m][n] = __builtin_amdgcn_mfma_f32_16x16x32_bf16(af[m], bfr[n], acc[m][n], 0, 0, 0);
    __syncthreads();
  }

  // ---- epilogue: RoPE for Q/K, transpose-store for V ----
  const int gcolbase = n0 + wc * 64;
  const int mat = gcolbase >> 9;               // 0:Q 1:K 2:V (block fully inside one matrix)
  const int bidx = m0 >> 9;
  if (mat < 2) {
    u16* dst = (mat == 0) ? Qb : Kb;
#pragma unroll
    for (int n = 0; n < 4; ++n) {
      int gcol = gcolbase + n * 16 + l16;
      int nc = gcol & 511;
      int dd = nc & 63;
      int fi = dd >> 1;
#pragma unroll
      for (int m = 0; m < 4; ++m)
#pragma unroll
        for (int r = 0; r < 4; ++r) {
          int row = m0 + wr * 64 + m * 16 + lg * 4 + r;
          int t = row & (TSEQ - 1);
          float v = acc[m][n][r];
          float o = __shfl_xor(v, 1);          // RoPE partner column
          float c = cosT[t * 32 + fi];
          float sn = sinT[t * 32 + fi];
          float res = (dd & 1) ? (v * c + o * sn) : (v * c - o * sn);
          dst[(size_t)row * CDIM + nc] = f2b(res);
        }
    }
  } else {
    // V: store transposed as VT[(b*8+h)*64+d][t]
#pragma unroll
    for (int n = 0; n < 4; ++n) {
      int gcol = gcolbase + n * 16 + l16;
      int nc = gcol & 511;
      int hh = nc >> 6, dd = nc & 63;
#pragma unroll
      for (int m = 0; m < 4; ++m) {
        int tb = (m0 & (TSEQ - 1)) + wr * 64 + m * 16 + lg * 4;
        ushort4 pk;
        pk.x = f2b(acc[m][n][0]); pk.y = f2b(acc[m][n][1]);
        pk.z = f2b(acc[m][n][2]); pk.w = f2b(acc[m][n][3]);
        *reinterpret_cast<ushort4*>(
            VT + (size_t)((bidx * NH + hh) * HS + dd) * TSEQ + tb) = pk;
      }
    }
  }
}

// ---------------- flash attention ----------------
// grid (B*H, TSEQ/64), block 256. Each wave owns 16 q-rows.
__global__ __launch_bounds__(256) void attn_kern(const u16* __restrict__ Qb,
                                                 const u16* __restrict__ Kb,
                                                 const u16* __restrict__ VT,
                                                 u16* __restrict__ att) {
  __shared__ __align__(16) u16 plds[4][16][32];
  const int lane = threadIdx.x & 63, wid = threadIdx.x >> 6;
  const int l16 = lane & 15, lg = lane >> 4;
  const int bh = blockIdx.x, b = bh >> 3, h = bh & 7;
  const int q0 = blockIdx.y * 64 + wid * 16;

  bf16x8 qf[2];
#pragma unroll
  for (int dc = 0; dc < 2; ++dc)
    qf[dc] = *reinterpret_cast<const bf16x8*>(
        Qb + (size_t)(b * TSEQ + q0 + l16) * CDIM + h * HS + dc * 32 + lg * 8);

  float m_r[4], l_r[4];
  f32x4 of[4] = {};
#pragma unroll
  for (int r = 0; r < 4; ++r) { m_r[r] = -1e30f; l_r[r] = 0.0f; }

  const int nkt = (q0 + 16 + 31) >> 5;
  for (int kt = 0; kt < nkt; ++kt) {
    f32x4 s[2] = {};
#pragma unroll
    for (int dc = 0; dc < 2; ++dc) {
      bf16x8 kf0 = *reinterpret_cast<const bf16x8*>(
          Kb + (size_t)(b * TSEQ + kt * 32 + l16) * CDIM + h * HS + dc * 32 + lg * 8);
      bf16x8 kf1 = *reinterpret_cast<const bf16x8*>(
          Kb + (size_t)(b * TSEQ + kt * 32 + 16 + l16) * CDIM + h * HS + dc * 32 + lg * 8);
      s[0] = __builtin_amdgcn_mfma_f32_16x16x32_bf16(qf[dc], kf0, s[0], 0, 0, 0);
      s[1] = __builtin_amdgcn_mfma_f32_16x16x32_bf16(qf[dc], kf1, s[1], 0, 0, 0);
    }
    float pm[4];
#pragma unroll
    for (int r = 0; r < 4; ++r) {
      int qg = q0 + lg * 4 + r;
      float v0 = s[0][r] * 0.125f;
      float v1 = s[1][r] * 0.125f;
      if (kt * 32 + l16 > qg) v0 = -1e30f;
      if (kt * 32 + 16 + l16 > qg) v1 = -1e30f;
      s[0][r] = v0; s[1][r] = v1;
      pm[r] = fmaxf(v0, v1);
    }
#pragma unroll
    for (int off = 1; off < 16; off <<= 1)
#pragma unroll
      for (int r = 0; r < 4; ++r) pm[r] = fmaxf(pm[r], __shfl_xor(pm[r], off));
#pragma unroll
    for (int r = 0; r < 4; ++r) {
      float mn = fmaxf(m_r[r], pm[r]);
      float alpha = __expf(m_r[r] - mn);
      m_r[r] = mn;
      float p0 = __expf(s[0][r] - mn);
      float p1 = __expf(s[1][r] - mn);
      s[0][r] = p0; s[1][r] = p1;
      float ts = p0 + p1;
#pragma unroll
      for (int off = 1; off < 16; off <<= 1) ts += __shfl_xor(ts, off);
      l_r[r] = l_r[r] * alpha + ts;
#pragma unroll
      for (int d = 0; d < 4; ++d) of[d][r] *= alpha;
    }
    // P (C-layout) -> LDS -> A-layout fragment
#pragma unroll
    for (int r = 0; r < 4; ++r) {
      plds[wid][lg * 4 + r][l16]      = f2b(s[0][r]);
      plds[wid][lg * 4 + r][16 + l16] = f2b(s[1][r]);
    }
    bf16x8 pf = *reinterpret_cast<const bf16x8*>(&plds[wid][l16][lg * 8]);
#pragma unroll
    for (int d = 0; d < 4; ++d) {
      bf16x8 vf = *reinterpret_cast<const bf16x8*>(
          VT + (size_t)(bh * HS + d * 16 + l16) * TSEQ + kt * 32 + lg * 8);
      of[d] = __builtin_amdgcn_mfma_f32_16x16x32_bf16(pf, vf, of[d], 0, 0, 0);
    }
  }
#pragma unroll
  for (int d = 0; d < 4; ++d)
#pragma unroll
    for (int r = 0; r < 4; ++r) {
      float v = of[d][r] / l_r[r];
      att[(size_t)(b * TSEQ + q0 + lg * 4 + r) * CDIM + h * HS + d * 16 + l16] = f2b(v);
    }
}

// ---------------- output projection (m97 structure) ----------------
__global__ __launch_bounds__(256) void out_gemm(const u16* __restrict__ A,
                                                const u16* __restrict__ WT,
                                                const float* __restrict__ bias,
                                                float* __restrict__ out) {
  __shared__ __align__(16) u16 lsA[BM * BK];
  __shared__ __align__(16) u16 lsB[BN * BK];
  const int tid = threadIdx.x;
  const int lane = tid & 63;
  const int l16 = lane & 15, lg = lane >> 4;
  const int wid = tid >> 6;
  const int wr = wid >> 1, wc = wid & 1;
  const int m0 = blockIdx.x * BM;
  const int n0 = blockIdx.y * BN;

  const u16* gA = A + (size_t)m0 * CDIM;
  const u16* gB = WT + (size_t)n0 * CDIM;

  f32x4 acc[4][4] = {};

  for (int kt = 0; kt < CDIM; kt += BK) {
#pragma unroll
    for (int c = 0; c < 2; ++c) {
      int flat = c * 2048 + tid * 8;
      int row = flat >> 5, col = flat & 31;
      gload_lds16(gA + (size_t)row * CDIM + kt + col, lsA + flat);
      gload_lds16(gB + (size_t)row * CDIM + kt + col, lsB + flat);
    }
    __syncthreads();
    bf16x8 af[4], bfr[4];
#pragma unroll
    for (int m = 0; m < 4; ++m)
      af[m] = *reinterpret_cast<const bf16x8*>(lsA + (wr * 64 + m * 16 + l16) * BK + lg * 8);
#pragma unroll
    for (int n = 0; n < 4; ++n)
      bfr[n] = *reinterpret_cast<const bf16x8*>(lsB + (wc * 64 + n * 16 + l16) * BK + lg * 8);
#pragma unroll
    for (int m = 0; m < 4; ++m)
#pragma unroll
      for (int n = 0; n < 4; ++n)
        acc[m][n] = __builtin_amdgcn_mfma_f32_16x16x32_bf16(af[m], bfr[n], acc[m][n], 0, 0, 0);
    __syncthreads();
  }

#pragma unroll
  for (int n = 0; n < 4; ++n) {
    int col = n0 + wc * 64 + n * 16 + l16;
    float bv = bias[col];
#pragma unroll
    for (int m = 0; m < 4; ++m)
#pragma unroll
      for (int r = 0; r < 4; ++r) {
        int row = m0 + wr * 64 + m * 16 + lg * 4 + r;
        out[(size_t)row * CDIM + col] = acc[m][n][r] + bv;
      }
  }
}

// ---------------- launcher ----------------
extern "C" void kernel_launch(void* const* d_in, const int* in_sizes, int n_in,
                              void* d_out, int out_size, void* d_ws, size_t ws_size,
                              hipStream_t stream) {
  const float* x  = (const float*)d_in[0];
  const float* Wq = (const float*)d_in[1];
  const float* Wk = (const float*)d_in[2];
  const float* Wv = (const float*)d_in[3];
  const float* Wo = (const float*)d_in[4];
  const float* bo = (const float*)d_in[5];
  float* out = (float*)d_out;

  char* p = (char*)d_ws;
  const size_t big = (size_t)MROWS * CDIM * 2;     // 16.78 MB per bf16 activation
  u16* xb   = (u16*)p;  p += big;
  u16* wtA  = (u16*)p;  p += (size_t)3 * CDIM * CDIM * 2;
  u16* woT  = (u16*)p;  p += (size_t)CDIM * CDIM * 2;
  float* cosT = (float*)p; p += (size_t)TSEQ * 32 * 4;
  float* sinT = (float*)p; p += (size_t)TSEQ * 32 * 4;
  u16* Qb   = (u16*)p;  p += big;
  u16* Kb   = (u16*)p;  p += big;
  u16* VT   = (u16*)p;  p += big;
  u16* att  = (u16*)p;  p += big;

  hipLaunchKernelGGL(conv_x, dim3(MROWS * CDIM / 4 / 256), dim3(256), 0, stream, x, xb);
  hipLaunchKernelGGL(transpose_w, dim3(16, 16, 4), dim3(32, 8), 0, stream,
                     Wq, Wk, Wv, Wo, wtA, woT);
  hipLaunchKernelGGL(rope_tab, dim3(TSEQ * 32 / 256), dim3(256), 0, stream, cosT, sinT);
  hipLaunchKernelGGL(qkv_gemm, dim3(MROWS / BM, 1536 / BN), dim3(256), 0, stream,
                     xb, wtA, cosT, sinT, Qb, Kb, VT);
  hipLaunchKernelGGL(attn_kern, dim3(BBATCH * NH, TSEQ / 64), dim3(256), 0, stream,
                     Qb, Kb, VT, att);
  hipLaunchKernelGGL(out_gemm, dim3(MROWS / BM, CDIM / BN), dim3(256), 0, stream,
                     att, woT, bo, out);
}

// Round 3
// 125.877 us; speedup vs baseline: 3.0222x; 1.2408x over previous
//
#include <hip/hip_runtime.h>

#define TSEQ 512
#define CDIM 512
#define NH 8
#define HS 64
#define BBATCH 32
#define MROWS (BBATCH * TSEQ)   // 16384

#define BM 128
#define BN 128
#define BK 32

typedef unsigned short u16;
typedef __bf16 bf16x8 __attribute__((ext_vector_type(8)));
typedef float f32x4 __attribute__((ext_vector_type(4)));
typedef float f32x16 __attribute__((ext_vector_type(16)));

// round-to-nearest-even fp32 -> bf16 bits
__device__ __forceinline__ u16 f2b(float f) {
  union { float f; unsigned u; } v; v.f = f;
  unsigned r = (v.u + 0x7fffu + ((v.u >> 16) & 1u)) >> 16;
  return (u16)r;
}

__device__ __forceinline__ void gload_lds16(const u16* g, u16* l) {
  __builtin_amdgcn_global_load_lds(
      (const __attribute__((address_space(1))) void*)g,
      (__attribute__((address_space(3))) void*)l, 16, 0, 0);
}

// ---------------- prep kernels ----------------

__global__ __launch_bounds__(256) void conv_x(const float* __restrict__ x,
                                              u16* __restrict__ xb) {
  int i = blockIdx.x * 256 + threadIdx.x;       // MROWS*CDIM/4 elements
  float4 v = reinterpret_cast<const float4*>(x)[i];
  ushort4 o;
  o.x = f2b(v.x); o.y = f2b(v.y); o.z = f2b(v.z); o.w = f2b(v.w);
  reinterpret_cast<ushort4*>(xb)[i] = o;
}

// transpose Wq,Wk,Wv -> wtA[1536][512] bf16 ; Wo -> woT[512][512] bf16
__global__ __launch_bounds__(256) void transpose_w(const float* __restrict__ wq,
                                                   const float* __restrict__ wk,
                                                   const float* __restrict__ wv,
                                                   const float* __restrict__ wo,
                                                   u16* __restrict__ wtA,
                                                   u16* __restrict__ woT) {
  __shared__ float tile[32][33];
  int mat = blockIdx.z;
  const float* src = (mat == 0) ? wq : (mat == 1) ? wk : (mat == 2) ? wv : wo;
  u16* dst = (mat < 3) ? (wtA + (size_t)mat * CDIM * CDIM) : woT;
  int kb = blockIdx.x * 32, nb = blockIdx.y * 32;
  int tx = threadIdx.x, ty = threadIdx.y;
#pragma unroll
  for (int rr = 0; rr < 32; rr += 8)
    tile[ty + rr][tx] = src[(size_t)(kb + ty + rr) * CDIM + nb + tx];
  __syncthreads();
#pragma unroll
  for (int rr = 0; rr < 32; rr += 8)
    dst[(size_t)(nb + ty + rr) * CDIM + kb + tx] = f2b(tile[tx][ty + rr]);
}

__global__ __launch_bounds__(256) void rope_tab(float* __restrict__ cosT,
                                                float* __restrict__ sinT) {
  int i = blockIdx.x * 256 + threadIdx.x;       // 512*32
  int t = i >> 5, f = i & 31;
  float inv = __powf(10000.0f, -(float)f / 32.0f);
  float ang = (float)t * inv;
  cosT[i] = cosf(ang);
  sinT[i] = sinf(ang);
}

// ---------------- fused QKV GEMM + RoPE (m97 structure) ----------------
__global__ __launch_bounds__(256) void qkv_gemm(const u16* __restrict__ xb,
                                                const u16* __restrict__ wtA,
                                                const float* __restrict__ cosT,
                                                const float* __restrict__ sinT,
                                                u16* __restrict__ Qb,
                                                u16* __restrict__ Kb,
                                                u16* __restrict__ VT) {
  __shared__ __align__(16) u16 lsA[BM * BK];   // 8 KB
  __shared__ __align__(16) u16 lsB[BN * BK];   // 8 KB
  const int tid = threadIdx.x;
  const int lane = tid & 63;
  const int l16 = lane & 15, lg = lane >> 4;
  const int wid = tid >> 6;
  const int wr = wid >> 1, wc = wid & 1;
  const int m0 = blockIdx.x * BM;
  const int n0 = blockIdx.y * BN;

  const u16* gA = xb + (size_t)m0 * CDIM;
  const u16* gB = wtA + (size_t)n0 * CDIM;

  f32x4 acc[4][4] = {};

  for (int kt = 0; kt < CDIM; kt += BK) {
#pragma unroll
    for (int c = 0; c < 2; ++c) {
      int flat = c * 2048 + tid * 8;           // element index in 128x32 tile
      int row = flat >> 5, col = flat & 31;
      gload_lds16(gA + (size_t)row * CDIM + kt + col, lsA + flat);
      gload_lds16(gB + (size_t)row * CDIM + kt + col, lsB + flat);
    }
    __syncthreads();
    bf16x8 af[4], bfr[4];
#pragma unroll
    for (int m = 0; m < 4; ++m)
      af[m] = *reinterpret_cast<const bf16x8*>(lsA + (wr * 64 + m * 16 + l16) * BK + lg * 8);
#pragma unroll
    for (int n = 0; n < 4; ++n)
      bfr[n] = *reinterpret_cast<const bf16x8*>(lsB + (wc * 64 + n * 16 + l16) * BK + lg * 8);
#pragma unroll
    for (int m = 0; m < 4; ++m)
#pragma unroll
      for (int n = 0; n < 4; ++n)
        acc[m][n] = __builtin_amdgcn_mfma_f32_16x16x32_bf16(af[m], bfr[n], acc[m][n], 0, 0, 0);
    __syncthreads();
  }

  // ---- epilogue: RoPE for Q/K, transpose-store for V ----
  const int gcolbase = n0 + wc * 64;
  const int mat = gcolbase >> 9;               // 0:Q 1:K 2:V
  const int bidx = m0 >> 9;
  if (mat < 2) {
    u16* dst = (mat == 0) ? Qb : Kb;
#pragma unroll
    for (int n = 0; n < 4; ++n) {
      int gcol = gcolbase + n * 16 + l16;
      int nc = gcol & 511;
      int dd = nc & 63;
      int fi = dd >> 1;
#pragma unroll
      for (int m = 0; m < 4; ++m)
#pragma unroll
        for (int r = 0; r < 4; ++r) {
          int row = m0 + wr * 64 + m * 16 + lg * 4 + r;
          int t = row & (TSEQ - 1);
          float v = acc[m][n][r];
          float o = __shfl_xor(v, 1);          // RoPE partner column
          float c = cosT[t * 32 + fi];
          float sn = sinT[t * 32 + fi];
          float res = (dd & 1) ? (v * c + o * sn) : (v * c - o * sn);
          dst[(size_t)row * CDIM + nc] = f2b(res);
        }
    }
  } else {
    // V: store transposed as VT[(b*8+h)*64+d][t]
#pragma unroll
    for (int n = 0; n < 4; ++n) {
      int gcol = gcolbase + n * 16 + l16;
      int nc = gcol & 511;
      int hh = nc >> 6, dd = nc & 63;
#pragma unroll
      for (int m = 0; m < 4; ++m) {
        int tb = (m0 & (TSEQ - 1)) + wr * 64 + m * 16 + lg * 4;
        ushort4 pk;
        pk.x = f2b(acc[m][n][0]); pk.y = f2b(acc[m][n][1]);
        pk.z = f2b(acc[m][n][2]); pk.w = f2b(acc[m][n][3]);
        *reinterpret_cast<ushort4*>(
            VT + (size_t)((bidx * NH + hh) * HS + dd) * TSEQ + tb) = pk;
      }
    }
  }
}

// ---------------- flash attention (m214-style, swapped QK^T, 32x32 MFMA) ----
// grid (B*H, TSEQ/128), block 256 (4 waves). Each wave: 32 q-rows, lane owns
// ONE q-column (q = q0 + (lane&31)); softmax is lane-local. No LDS.
__global__ __launch_bounds__(256, 4) void attn_kern(const u16* __restrict__ Qb,
                                                    const u16* __restrict__ Kb,
                                                    const u16* __restrict__ VT,
                                                    u16* __restrict__ att) {
  const int lane = threadIdx.x & 63, wid = threadIdx.x >> 6;
  const int l31 = lane & 31, hh = lane >> 5;
  const int bh = blockIdx.x, b = bh >> 3, h = bh & 7;
  const int q0 = blockIdx.y * 128 + wid * 32;

  // Q as MFMA B-fragment (col = q = l31, k-elems = d = ds*16 + hh*8 + j)
  bf16x8 qf[4];
  const u16* qbase = Qb + (size_t)(b * TSEQ + q0 + l31) * CDIM + h * HS + hh * 8;
#pragma unroll
  for (int ds = 0; ds < 4; ++ds)
    qf[ds] = *reinterpret_cast<const bf16x8*>(qbase + ds * 16);

  const float SC = 0.125f * 1.4426950408889634f;  // scale * log2(e)
  float m_r = -1e30f, lsum = 0.0f;
  f32x16 of[2] = {};   // O^T[d][q]: of[dt], d = dt*32 + (r&3)+8*(r>>2)+4*hh

  const int nkt = (q0 >> 5) + 1;
  for (int kt = 0; kt < nkt; ++kt) {
    // S^T[k][q] = mfma(K as A, Q as B)
    f32x16 s = {};
    const u16* kr = Kb + (size_t)(b * TSEQ + kt * 32 + l31) * CDIM + h * HS + hh * 8;
#pragma unroll
    for (int ds = 0; ds < 4; ++ds) {
      bf16x8 kf = *reinterpret_cast<const bf16x8*>(kr + ds * 16);
      s = __builtin_amdgcn_mfma_f32_32x32x16_bf16(kf, qf[ds], s, 0, 0, 0);
    }
    float p[16];
#pragma unroll
    for (int r = 0; r < 16; ++r) p[r] = s[r] * SC;
    if (kt == nkt - 1) {          // diagonal tile: mask k > q
#pragma unroll
      for (int r = 0; r < 16; ++r) {
        int kk = (r & 3) + 8 * (r >> 2) + 4 * hh;
        if (kk > l31) p[r] = -1e30f;
      }
    }
    float pm = p[0];
#pragma unroll
    for (int r = 1; r < 16; ++r) pm = fmaxf(pm, p[r]);
    pm = fmaxf(pm, __shfl_xor(pm, 32));
    if (!__all(pm - m_r <= 8.0f)) {   // T13 defer-max
      float mn = fmaxf(m_r, pm);
      float alpha = exp2f(m_r - mn);
      m_r = mn;
      lsum *= alpha;
#pragma unroll
      for (int r = 0; r < 16; ++r) { of[0][r] *= alpha; of[1][r] *= alpha; }
    }
    float ts = 0.0f;
#pragma unroll
    for (int r = 0; r < 16; ++r) { p[r] = exp2f(p[r] - m_r); ts += p[r]; }
    ts += __shfl_xor(ts, 32);
    lsum += ts;

    // P^T -> bf16 B-fragments via cvt_pk + permlane32_swap (T12)
    unsigned w0, w1, w2, w3, w4, w5, w6, w7;
    asm("v_cvt_pk_bf16_f32 %0, %1, %2" : "=v"(w0) : "v"(p[0]),  "v"(p[1]));
    asm("v_cvt_pk_bf16_f32 %0, %1, %2" : "=v"(w1) : "v"(p[2]),  "v"(p[3]));
    asm("v_cvt_pk_bf16_f32 %0, %1, %2" : "=v"(w2) : "v"(p[4]),  "v"(p[5]));
    asm("v_cvt_pk_bf16_f32 %0, %1, %2" : "=v"(w3) : "v"(p[6]),  "v"(p[7]));
    asm("v_cvt_pk_bf16_f32 %0, %1, %2" : "=v"(w4) : "v"(p[8]),  "v"(p[9]));
    asm("v_cvt_pk_bf16_f32 %0, %1, %2" : "=v"(w5) : "v"(p[10]), "v"(p[11]));
    asm("v_cvt_pk_bf16_f32 %0, %1, %2" : "=v"(w6) : "v"(p[12]), "v"(p[13]));
    asm("v_cvt_pk_bf16_f32 %0, %1, %2" : "=v"(w7) : "v"(p[14]), "v"(p[15]));
    // w0=k{0,1}+4h w1=k{2,3}+4h w2=k{8,9}+4h w3=k{10,11}+4h (kstep0)
    // w4..w7 same +16 (kstep1)
    asm("v_permlane32_swap_b32 %0, %1" : "+v"(w0), "+v"(w2));
    asm("v_permlane32_swap_b32 %0, %1" : "+v"(w1), "+v"(w3));
    asm("v_permlane32_swap_b32 %0, %1" : "+v"(w4), "+v"(w6));
    asm("v_permlane32_swap_b32 %0, %1" : "+v"(w5), "+v"(w7));
    union { unsigned u[4]; bf16x8 v; } pb0, pb1;
    pb0.u[0] = w0; pb0.u[1] = w1; pb0.u[2] = w2; pb0.u[3] = w3;
    pb1.u[0] = w4; pb1.u[1] = w5; pb1.u[2] = w6; pb1.u[3] = w7;

    // O^T[dt] += V^T[dt][k] . P^T[k][q]
    const u16* vr = VT + (size_t)(bh * HS + l31) * TSEQ + kt * 32 + hh * 8;
    bf16x8 vf00 = *reinterpret_cast<const bf16x8*>(vr);
    bf16x8 vf01 = *reinterpret_cast<const bf16x8*>(vr + 16);
    bf16x8 vf10 = *reinterpret_cast<const bf16x8*>(vr + 32 * TSEQ);
    bf16x8 vf11 = *reinterpret_cast<const bf16x8*>(vr + 32 * TSEQ + 16);
    of[0] = __builtin_amdgcn_mfma_f32_32x32x16_bf16(vf00, pb0.v, of[0], 0, 0, 0);
    of[0] = __builtin_amdgcn_mfma_f32_32x32x16_bf16(vf01, pb1.v, of[0], 0, 0, 0);
    of[1] = __builtin_amdgcn_mfma_f32_32x32x16_bf16(vf10, pb0.v, of[1], 0, 0, 0);
    of[1] = __builtin_amdgcn_mfma_f32_32x32x16_bf16(vf11, pb1.v, of[1], 0, 0, 0);
  }

  float inv = 1.0f / lsum;
  u16* obase = att + (size_t)(b * TSEQ + q0 + l31) * CDIM + h * HS;
#pragma unroll
  for (int dt = 0; dt < 2; ++dt)
#pragma unroll
    for (int i = 0; i < 8; ++i) {
      ushort2 st;
      st.x = f2b(of[dt][2 * i] * inv);
      st.y = f2b(of[dt][2 * i + 1] * inv);
      int d = dt * 32 + ((2 * i) & 3) + 8 * ((2 * i) >> 2) + 4 * hh;
      *reinterpret_cast<ushort2*>(obase + d) = st;
    }
}

// ---------------- output projection (m97 structure) ----------------
__global__ __launch_bounds__(256) void out_gemm(const u16* __restrict__ A,
                                                const u16* __restrict__ WT,
                                                const float* __restrict__ bias,
                                                float* __restrict__ out) {
  __shared__ __align__(16) u16 lsA[BM * BK];
  __shared__ __align__(16) u16 lsB[BN * BK];
  const int tid = threadIdx.x;
  const int lane = tid & 63;
  const int l16 = lane & 15, lg = lane >> 4;
  const int wid = tid >> 6;
  const int wr = wid >> 1, wc = wid & 1;
  const int m0 = blockIdx.x * BM;
  const int n0 = blockIdx.y * BN;

  const u16* gA = A + (size_t)m0 * CDIM;
  const u16* gB = WT + (size_t)n0 * CDIM;

  f32x4 acc[4][4] = {};

  for (int kt = 0; kt < CDIM; kt += BK) {
#pragma unroll
    for (int c = 0; c < 2; ++c) {
      int flat = c * 2048 + tid * 8;
      int row = flat >> 5, col = flat & 31;
      gload_lds16(gA + (size_t)row * CDIM + kt + col, lsA + flat);
      gload_lds16(gB + (size_t)row * CDIM + kt + col, lsB + flat);
    }
    __syncthreads();
    bf16x8 af[4], bfr[4];
#pragma unroll
    for (int m = 0; m < 4; ++m)
      af[m] = *reinterpret_cast<const bf16x8*>(lsA + (wr * 64 + m * 16 + l16) * BK + lg * 8);
#pragma unroll
    for (int n = 0; n < 4; ++n)
      bfr[n] = *reinterpret_cast<const bf16x8*>(lsB + (wc * 64 + n * 16 + l16) * BK + lg * 8);
#pragma unroll
    for (int m = 0; m < 4; ++m)
#pragma unroll
      for (int n = 0; n < 4; ++n)
        acc[m][n] = __builtin_amdgcn_mfma_f32_16x16x32_bf16(af[m], bfr[n], acc[m][n], 0, 0, 0);
    __syncthreads();
  }

#pragma unroll
  for (int n = 0; n < 4; ++n) {
    int col = n0 + wc * 64 + n * 16 + l16;
    float bv = bias[col];
#pragma unroll
    for (int m = 0; m < 4; ++m)
#pragma unroll
      for (int r = 0; r < 4; ++r) {
        int row = m0 + wr * 64 + m * 16 + lg * 4 + r;
        out[(size_t)row * CDIM + col] = acc[m][n][r] + bv;
      }
  }
}

// ---------------- launcher ----------------
extern "C" void kernel_launch(void* const* d_in, const int* in_sizes, int n_in,
                              void* d_out, int out_size, void* d_ws, size_t ws_size,
                              hipStream_t stream) {
  const float* x  = (const float*)d_in[0];
  const float* Wq = (const float*)d_in[1];
  const float* Wk = (const float*)d_in[2];
  const float* Wv = (const float*)d_in[3];
  const float* Wo = (const float*)d_in[4];
  const float* bo = (const float*)d_in[5];
  float* out = (float*)d_out;

  char* p = (char*)d_ws;
  const size_t big = (size_t)MROWS * CDIM * 2;     // 16.78 MB per bf16 activation
  u16* xb   = (u16*)p;  p += big;
  u16* wtA  = (u16*)p;  p += (size_t)3 * CDIM * CDIM * 2;
  u16* woT  = (u16*)p;  p += (size_t)CDIM * CDIM * 2;
  float* cosT = (float*)p; p += (size_t)TSEQ * 32 * 4;
  float* sinT = (float*)p; p += (size_t)TSEQ * 32 * 4;
  u16* Qb   = (u16*)p;  p += big;
  u16* Kb   = (u16*)p;  p += big;
  u16* VT   = (u16*)p;  p += big;
  u16* att  = (u16*)p;  p += big;

  hipLaunchKernelGGL(conv_x, dim3(MROWS * CDIM / 4 / 256), dim3(256), 0, stream, x, xb);
  hipLaunchKernelGGL(transpose_w, dim3(16, 16, 4), dim3(32, 8), 0, stream,
                     Wq, Wk, Wv, Wo, wtA, woT);
  hipLaunchKernelGGL(rope_tab, dim3(TSEQ * 32 / 256), dim3(256), 0, stream, cosT, sinT);
  hipLaunchKernelGGL(qkv_gemm, dim3(MROWS / BM, 1536 / BN), dim3(256), 0, stream,
                     xb, wtA, cosT, sinT, Qb, Kb, VT);
  hipLaunchKernelGGL(attn_kern, dim3(BBATCH * NH, TSEQ / 128), dim3(256), 0, stream,
                     Qb, Kb, VT, att);
  hipLaunchKernelGGL(out_gemm, dim3(MROWS / BM, CDIM / BN), dim3(256), 0, stream,
                     att, woT, bo, out);
}